// Round 5
// baseline (399.456 us; speedup 1.0000x reference)
//
#include <hip/hip_runtime.h>
#include <float.h>
#include <math.h>

#define NNODES 100000
#define NEDGES 800000
#define NF 128
#define NCLASSES 10
#define NGRAPHS 256

#define NBUCK 1563            // ceil(100000 / 64) dst-buckets of 64 nodes
#define BF_CH 3125            // 800000 / 256 edges per virtual block in binfill

typedef __attribute__((ext_vector_type(8))) short bf16x8;
typedef __attribute__((ext_vector_type(4))) float f32x4;

__device__ inline ushort f2bf(float f) {  // fp32 -> bf16 RNE
    unsigned u = __float_as_uint(f);
    u = u + 0x7FFFu + ((u >> 16) & 1u);
    return (ushort)(u >> 16);
}
__device__ inline float b2f(ushort h) {
    return __uint_as_float(((unsigned)h) << 16);
}
// monotone fp32<->uint encoding: uint max order == float max order
__device__ inline unsigned fenc(float f) {
    unsigned u = __float_as_uint(f);
    return ((int)u < 0) ? ~u : (u | 0x80000000u);
}
__device__ inline float fdec(unsigned s) {
    return (s & 0x80000000u) ? __uint_as_float(s ^ 0x80000000u) : __uint_as_float(~s);
}

// ---------------- bucket histogram: bcnt[b] = #edges with dst in bucket b ----------------
__global__ __launch_bounds__(256) void bincnt_kernel(const int* __restrict__ dst,
                                                     unsigned* __restrict__ bcnt, int E) {
    __shared__ unsigned lh[NBUCK];
    for (int i = threadIdx.x; i < NBUCK; i += 256) lh[i] = 0;
    __syncthreads();
    for (int e = blockIdx.x * 256 + threadIdx.x; e < E; e += gridDim.x * 256)
        atomicAdd(&lh[dst[e] >> 6], 1u);
    __syncthreads();
    for (int i = threadIdx.x; i < NBUCK; i += 256) {
        unsigned v = lh[i];
        if (v) atomicAdd(&bcnt[i], v);
    }
}

// ---------------- single-block exclusive scan (used for 1563 bucket counts) ----------------
__global__ __launch_bounds__(1024) void scan_kernel(const unsigned* __restrict__ cnt,
                                                    unsigned* __restrict__ outp,
                                                    unsigned* __restrict__ outc, int N) {
    __shared__ unsigned wsum[16];
    __shared__ unsigned wpre[16];
    int tid = threadIdx.x;
    int wid = tid >> 6, lane = tid & 63;
    unsigned carry = 0;
    for (int base = 0; base < N; base += 1024) {
        int i = base + tid;
        unsigned v = (i < N) ? cnt[i] : 0u;
        unsigned incl = v;
        #pragma unroll
        for (int off = 1; off < 64; off <<= 1) {
            unsigned t = __shfl_up(incl, off, 64);
            if (lane >= off) incl += t;
        }
        if (lane == 63) wsum[wid] = incl;
        __syncthreads();
        if (tid < 16) {
            unsigned s = wsum[tid];
            unsigned inc2 = s;
            #pragma unroll
            for (int off = 1; off < 16; off <<= 1) {
                unsigned t = __shfl_up(inc2, off, 64);
                if (tid >= off) inc2 += t;
            }
            wpre[tid] = inc2 - s;
        }
        __syncthreads();
        unsigned excl = incl - v + wpre[wid] + carry;
        if (i < N) { outp[i] = excl; outc[i] = excl; }
        unsigned total = wpre[15] + wsum[15];
        __syncthreads();
        carry += total;
    }
    if (tid == 0) outp[N] = carry;
}

// ---------------- binfill: scatter edges into bucket-ordered bedge, XCD-affine ----------------
// blockIdx&7 selects the bucket residue class; consecutive blockIdx round-robin across
// XCDs, so each bucket's frontier lines are written by (mostly) one XCD -> compact evictions.
__global__ __launch_bounds__(256) void binfill_kernel(const int* __restrict__ src,
                                                      const int* __restrict__ dst,
                                                      unsigned* __restrict__ bcur,
                                                      unsigned* __restrict__ bedge, int E) {
    int vb = blockIdx.x >> 3;
    int r = blockIdx.x & 7;
    int e0 = vb * BF_CH;
    int e1 = e0 + BF_CH;  // E == 256*BF_CH exactly
    for (int e = e0 + threadIdx.x; e < e1; e += 256) {
        int d = dst[e];
        int b = d >> 6;
        if ((b & 7) != r) continue;
        int s = src[e];
        unsigned pos = atomicAdd(&bcur[b], 1u);
        bedge[pos] = ((unsigned)s << 6) | (unsigned)(d & 63);
    }
}

// ---------------- bucket kernel: per-node counts, rowptr, dinv, csr placement ----------------
// one block per bucket (64 nodes). rowptr comes from bucket base + LDS prefix -> no
// global node-level scan needed. csr writes land in this bucket's private window.
__global__ __launch_bounds__(256) void bucket_kernel(const unsigned* __restrict__ bedge,
                                                     const unsigned* __restrict__ bptr,
                                                     float* __restrict__ dinv,
                                                     unsigned* __restrict__ rowptr,
                                                     unsigned* __restrict__ csr_src, int N) {
    __shared__ unsigned lcnt[64];
    __shared__ unsigned lcur[64];
    int b = blockIdx.x;
    int tid = threadIdx.x;
    unsigned ebeg = bptr[b], eend = bptr[b + 1];
    if (tid < 64) lcnt[tid] = 0;
    __syncthreads();
    for (unsigned e = ebeg + tid; e < eend; e += 256)
        atomicAdd(&lcnt[bedge[e] & 63], 1u);
    __syncthreads();
    if (tid < 64) {  // wave 0: scan 64 per-node counts
        unsigned c = lcnt[tid];
        unsigned incl = c;
        #pragma unroll
        for (int off = 1; off < 64; off <<= 1) {
            unsigned t = __shfl_up(incl, off, 64);
            if (tid >= off) incl += t;
        }
        unsigned pref = incl - c;
        int node = b * 64 + tid;
        if (node < N) {
            rowptr[node] = ebeg + pref;
            dinv[node] = rsqrtf((float)c + 1.0f);
        }
        lcur[tid] = ebeg + pref;
    }
    if (b == (int)gridDim.x - 1 && tid == 0) rowptr[N] = eend;  // = NEDGES
    __syncthreads();
    for (unsigned e = ebeg + tid; e < eend; e += 256) {
        unsigned v = bedge[e];
        unsigned pos = atomicAdd(&lcur[v & 63], 1u);
        csr_src[pos] = v >> 6;
    }
}

// ---------------- W -> lane-ordered bf16 MFMA fragments ----------------
__global__ __launch_bounds__(256) void wprep_kernel(const float* __restrict__ Ws,
                                                    short* __restrict__ Wf) {
    int l = blockIdx.x;
    for (int idx = threadIdx.x; idx < 16384; idx += 256) {
        int i = idx & 7;
        int lane = (idx >> 3) & 63;
        int ns = idx >> 9;
        int s = ns & 3, nt = ns >> 2;
        int k = s * 32 + (lane >> 4) * 8 + i;
        int n = nt * 16 + (lane & 15);
        Wf[l * 16384 + idx] = (short)f2bf(Ws[l * 16384 + k * NF + n]);
    }
}

// ---------------- H = X @ W via bf16 MFMA; output bf16 ----------------
template<bool L0>
__global__ __launch_bounds__(256) void gemm_mfma_kernel(const void* __restrict__ Xin,
                                                        const short* __restrict__ Wf,
                                                        ushort* __restrict__ Hb, int M) {
    __shared__ short Wl[16384];
    int tid = threadIdx.x;
    for (int i = tid; i < 2048; i += 256)
        ((float4*)Wl)[i] = ((const float4*)Wf)[i];

    int wave = tid >> 6, lane = tid & 63;
    int r = lane & 15, kg = lane >> 4;
    int rowbase = blockIdx.x * 128 + wave * 32;

    bf16x8 afrag[2][4];
    #pragma unroll
    for (int t = 0; t < 2; ++t) {
        #pragma unroll
        for (int s = 0; s < 4; ++s) {
            int row = rowbase + t * 16 + r;
            if (row > M - 1) row = M - 1;
            if (L0) {
                const float* p = (const float*)Xin + (size_t)row * NF + s * 32 + kg * 8;
                float4 u0 = *(const float4*)p;
                float4 u1 = *(const float4*)(p + 4);
                bf16x8 a;
                a[0] = (short)f2bf(u0.x); a[1] = (short)f2bf(u0.y);
                a[2] = (short)f2bf(u0.z); a[3] = (short)f2bf(u0.w);
                a[4] = (short)f2bf(u1.x); a[5] = (short)f2bf(u1.y);
                a[6] = (short)f2bf(u1.z); a[7] = (short)f2bf(u1.w);
                afrag[t][s] = a;
            } else {
                afrag[t][s] = *(const bf16x8*)((const ushort*)Xin + (size_t)row * NF + s * 32 + kg * 8);
            }
        }
    }

    f32x4 acc[2][8];
    #pragma unroll
    for (int t = 0; t < 2; ++t)
        #pragma unroll
        for (int n = 0; n < 8; ++n)
            acc[t][n] = (f32x4){0.f, 0.f, 0.f, 0.f};

    __syncthreads();
    const bf16x8* WL = (const bf16x8*)Wl;
    #pragma unroll
    for (int s = 0; s < 4; ++s) {
        #pragma unroll
        for (int n = 0; n < 8; ++n) {
            bf16x8 bfr = WL[(n * 4 + s) * 64 + lane];
            acc[0][n] = __builtin_amdgcn_mfma_f32_16x16x32_bf16(afrag[0][s], bfr, acc[0][n], 0, 0, 0);
            acc[1][n] = __builtin_amdgcn_mfma_f32_16x16x32_bf16(afrag[1][s], bfr, acc[1][n], 0, 0, 0);
        }
    }

    int r4 = kg * 4;
    #pragma unroll
    for (int t = 0; t < 2; ++t) {
        #pragma unroll
        for (int n = 0; n < 8; ++n) {
            #pragma unroll
            for (int q = 0; q < 4; ++q) {
                int row = rowbase + t * 16 + r4 + q;
                if (row < M) Hb[(size_t)row * NF + n * 16 + r] = f2bf(acc[t][n][q]);
            }
        }
    }
}

// ---------------- aggregate: bf16 gather, norm from dinv, fp32 math, bf16 out ----------------
__global__ __launch_bounds__(256) void aggregate_kernel(const ushort* __restrict__ Hb,
                                                        const float* __restrict__ dinv,
                                                        const unsigned* __restrict__ rowptr,
                                                        const unsigned* __restrict__ csr_src,
                                                        const float* __restrict__ bias,
                                                        ushort* __restrict__ Xout, int N) {
    int gid = blockIdx.x * 256 + threadIdx.x;
    int node = gid >> 5;
    int lane = gid & 31;
    if (node >= N) return;
    float di = dinv[node];
    float sl = di * di;
    float4 b = ((const float4*)bias)[lane];
    ushort4 hv = *(const ushort4*)(Hb + (size_t)node * NF + lane * 4);
    float ax = fmaf(b2f(hv.x), sl, b.x);
    float ay = fmaf(b2f(hv.y), sl, b.y);
    float az = fmaf(b2f(hv.z), sl, b.z);
    float aw = fmaf(b2f(hv.w), sl, b.w);
    unsigned e = rowptr[node], end = rowptr[node + 1];
    for (; e + 4 <= end; e += 4) {
        unsigned s0 = csr_src[e + 0], s1 = csr_src[e + 1];
        unsigned s2 = csr_src[e + 2], s3 = csr_src[e + 3];
        float n0 = dinv[s0] * di, n1 = dinv[s1] * di;
        float n2 = dinv[s2] * di, n3 = dinv[s3] * di;
        ushort4 g0 = *(const ushort4*)(Hb + (size_t)s0 * NF + lane * 4);
        ushort4 g1 = *(const ushort4*)(Hb + (size_t)s1 * NF + lane * 4);
        ushort4 g2 = *(const ushort4*)(Hb + (size_t)s2 * NF + lane * 4);
        ushort4 g3 = *(const ushort4*)(Hb + (size_t)s3 * NF + lane * 4);
        ax = fmaf(b2f(g0.x), n0, ax); ay = fmaf(b2f(g0.y), n0, ay);
        az = fmaf(b2f(g0.z), n0, az); aw = fmaf(b2f(g0.w), n0, aw);
        ax = fmaf(b2f(g1.x), n1, ax); ay = fmaf(b2f(g1.y), n1, ay);
        az = fmaf(b2f(g1.z), n1, az); aw = fmaf(b2f(g1.w), n1, aw);
        ax = fmaf(b2f(g2.x), n2, ax); ay = fmaf(b2f(g2.y), n2, ay);
        az = fmaf(b2f(g2.z), n2, az); aw = fmaf(b2f(g2.w), n2, aw);
        ax = fmaf(b2f(g3.x), n3, ax); ay = fmaf(b2f(g3.y), n3, ay);
        az = fmaf(b2f(g3.z), n3, az); aw = fmaf(b2f(g3.w), n3, aw);
    }
    for (; e < end; ++e) {
        unsigned s = csr_src[e];
        float nm = dinv[s] * di;
        ushort4 g = *(const ushort4*)(Hb + (size_t)s * NF + lane * 4);
        ax = fmaf(b2f(g.x), nm, ax); ay = fmaf(b2f(g.y), nm, ay);
        az = fmaf(b2f(g.z), nm, az); aw = fmaf(b2f(g.w), nm, aw);
    }
    ax = ax > 0.f ? ax : expm1f(ax);
    ay = ay > 0.f ? ay : expm1f(ay);
    az = az > 0.f ? az : expm1f(az);
    aw = aw > 0.f ? aw : expm1f(aw);
    ushort4 o;
    o.x = f2bf(ax); o.y = f2bf(ay); o.z = f2bf(az); o.w = f2bf(aw);
    *(ushort4*)(Xout + (size_t)node * NF + lane * 4) = o;
}

// ---------------- global max pool: node-parallel, atomicMax on monotone enc ----------------
__global__ __launch_bounds__(256) void pool_kernel(const ushort* __restrict__ X,
                                                   const int* __restrict__ batch,
                                                   unsigned* __restrict__ Gx, int N) {
    __shared__ int gb[256];
    int n0 = blockIdx.x * 256;
    int tid = threadIdx.x;
    {
        int n = n0 + tid;
        gb[tid] = (n < N) ? batch[n] : -1;
    }
    __syncthreads();
    int cg = tid & 31;
    int rg = tid >> 5;
    float mx = -FLT_MAX, my = -FLT_MAX, mz = -FLT_MAX, mw = -FLT_MAX;
    int curg = -1;
    for (int i = rg; i < 256; i += 8) {
        int n = n0 + i;
        if (n >= N) break;
        int g = gb[i];
        if (g != curg) {
            if (curg >= 0) {
                unsigned* p = Gx + (size_t)curg * NF + cg * 4;
                atomicMax(p + 0, fenc(mx)); atomicMax(p + 1, fenc(my));
                atomicMax(p + 2, fenc(mz)); atomicMax(p + 3, fenc(mw));
            }
            curg = g;
            mx = my = mz = mw = -FLT_MAX;
        }
        ushort4 v = *(const ushort4*)(X + (size_t)n * NF + cg * 4);
        mx = fmaxf(mx, b2f(v.x)); my = fmaxf(my, b2f(v.y));
        mz = fmaxf(mz, b2f(v.z)); mw = fmaxf(mw, b2f(v.w));
    }
    if (curg >= 0) {
        unsigned* p = Gx + (size_t)curg * NF + cg * 4;
        atomicMax(p + 0, fenc(mx)); atomicMax(p + 1, fenc(my));
        atomicMax(p + 2, fenc(mz)); atomicMax(p + 3, fenc(mw));
    }
}

// ---------------- classifier: softmax(decode(Gx) @ Wc + bc), fp32 ----------------
__global__ __launch_bounds__(128) void classify_kernel(const unsigned* __restrict__ Gx,
                                                       const float* __restrict__ Wc,
                                                       const float* __restrict__ bc,
                                                       float* __restrict__ out) {
    __shared__ float gr[NF];
    __shared__ float lg[NCLASSES];
    int g = blockIdx.x;
    int tid = threadIdx.x;
    gr[tid] = fdec(Gx[(size_t)g * NF + tid]);
    __syncthreads();
    if (tid < NCLASSES) {
        float s = bc[tid];
        for (int k = 0; k < NF; ++k) s = fmaf(gr[k], Wc[k * NCLASSES + tid], s);
        lg[tid] = s;
    }
    __syncthreads();
    if (tid == 0) {
        float m = lg[0];
        #pragma unroll
        for (int c = 1; c < NCLASSES; ++c) m = fmaxf(m, lg[c]);
        float e[NCLASSES];
        float sum = 0.f;
        #pragma unroll
        for (int c = 0; c < NCLASSES; ++c) { e[c] = expf(lg[c] - m); sum += e[c]; }
        #pragma unroll
        for (int c = 0; c < NCLASSES; ++c) out[g * NCLASSES + c] = e[c] / sum;
    }
}

extern "C" void kernel_launch(void* const* d_in, const int* in_sizes, int n_in,
                              void* d_out, int out_size, void* d_ws, size_t ws_size,
                              hipStream_t stream) {
    const float* x     = (const float*)d_in[0];
    const int*   ei    = (const int*)d_in[1];
    const int*   batch = (const int*)d_in[2];
    const float* Ws    = (const float*)d_in[3];
    const float* bs    = (const float*)d_in[4];
    const float* Wc    = (const float*)d_in[5];
    const float* bc    = (const float*)d_in[6];
    float* out = (float*)d_out;

    const int* src = ei;
    const int* dst = ei + NEDGES;

    char* ws = (char*)d_ws;
    size_t off = 0;
    auto alloc = [&](size_t bytes) -> void* {
        off = (off + 255) & ~(size_t)255;
        void* p = ws + off;
        off += bytes;
        return p;
    };
    ushort*   B0      = (ushort*)alloc(sizeof(ushort) * (size_t)NNODES * NF);
    ushort*   B1      = (ushort*)alloc(sizeof(ushort) * (size_t)NNODES * NF);
    ushort*   Hb      = (ushort*)alloc(sizeof(ushort) * (size_t)NNODES * NF);
    float*    dinvp   = (float*)alloc(sizeof(float) * NNODES);
    unsigned* rowptr  = (unsigned*)alloc(sizeof(unsigned) * (NNODES + 1));
    unsigned* csr_src = (unsigned*)alloc(sizeof(unsigned) * NEDGES);
    unsigned* bedge   = (unsigned*)alloc(sizeof(unsigned) * NEDGES);
    unsigned* bptr    = (unsigned*)alloc(sizeof(unsigned) * (NBUCK + 1));
    unsigned* bcur    = (unsigned*)alloc(sizeof(unsigned) * NBUCK);
    short*    Wf      = (short*)alloc(sizeof(short) * 3 * 16384);
    // zero-region: bcnt + Gx contiguous -> single memset
    unsigned* bcnt    = (unsigned*)alloc(sizeof(unsigned) * NBUCK);
    unsigned* Gx      = (unsigned*)alloc(sizeof(unsigned) * NGRAPHS * NF);
    size_t zspan = (size_t)((char*)(Gx + NGRAPHS * NF) - (char*)bcnt);

    hipMemsetAsync(bcnt, 0, zspan, stream);
    wprep_kernel<<<3, 256, 0, stream>>>(Ws, Wf);
    bincnt_kernel<<<128, 256, 0, stream>>>(dst, bcnt, NEDGES);
    scan_kernel<<<1, 1024, 0, stream>>>(bcnt, bptr, bcur, NBUCK);
    binfill_kernel<<<2048, 256, 0, stream>>>(src, dst, bcur, bedge, NEDGES);
    bucket_kernel<<<NBUCK, 256, 0, stream>>>(bedge, bptr, dinvp, rowptr, csr_src, NNODES);

    int gemm_grid = (NNODES + 127) / 128;   // 782
    int agg_grid  = (NNODES * 32) / 256;    // 12500 exact

    gemm_mfma_kernel<true><<<gemm_grid, 256, 0, stream>>>(x, Wf + 0 * 16384, Hb, NNODES);
    aggregate_kernel<<<agg_grid, 256, 0, stream>>>(Hb, dinvp, rowptr, csr_src, bs + 0 * NF, B1, NNODES);
    gemm_mfma_kernel<false><<<gemm_grid, 256, 0, stream>>>(B1, Wf + 1 * 16384, Hb, NNODES);
    aggregate_kernel<<<agg_grid, 256, 0, stream>>>(Hb, dinvp, rowptr, csr_src, bs + 1 * NF, B0, NNODES);
    gemm_mfma_kernel<false><<<gemm_grid, 256, 0, stream>>>(B0, Wf + 2 * 16384, Hb, NNODES);
    aggregate_kernel<<<agg_grid, 256, 0, stream>>>(Hb, dinvp, rowptr, csr_src, bs + 2 * NF, B1, NNODES);

    pool_kernel<<<(NNODES + 255) / 256, 256, 0, stream>>>(B1, batch, Gx, NNODES);
    classify_kernel<<<NGRAPHS, 128, 0, stream>>>(Gx, Wc, bc, out);
}

// Round 6
// 320.365 us; speedup vs baseline: 1.2469x; 1.2469x over previous
//
#include <hip/hip_runtime.h>
#include <float.h>
#include <math.h>

#define NNODES 100000
#define NEDGES 800000
#define NF 128
#define NCLASSES 10
#define NGRAPHS 256

#define SCAN_CHUNK 2048
#define SCAN_NB ((NNODES + SCAN_CHUNK - 1) / SCAN_CHUNK)  // 49

typedef __attribute__((ext_vector_type(8))) short bf16x8;
typedef __attribute__((ext_vector_type(4))) float f32x4;

__device__ inline ushort f2bf(float f) {  // fp32 -> bf16 RNE
    unsigned u = __float_as_uint(f);
    u = u + 0x7FFFu + ((u >> 16) & 1u);
    return (ushort)(u >> 16);
}
__device__ inline float b2f(ushort h) {
    return __uint_as_float(((unsigned)h) << 16);
}
// monotone fp32<->uint encoding: uint max order == float max order
__device__ inline unsigned fenc(float f) {
    unsigned u = __float_as_uint(f);
    return ((int)u < 0) ? ~u : (u | 0x80000000u);
}
__device__ inline float fdec(unsigned s) {
    return (s & 0x80000000u) ? __uint_as_float(s ^ 0x80000000u) : __uint_as_float(~s);
}

// ---------------- degree histogram (dst occurrences) ----------------
__global__ __launch_bounds__(256) void hist_kernel(const int* __restrict__ dst,
                                                   unsigned* __restrict__ cnt, int E) {
    int i = blockIdx.x * 256 + threadIdx.x;
    if (i < E) atomicAdd(&cnt[dst[i]], 1u);
}

// ---------------- multi-block exclusive scan ----------------
__global__ __launch_bounds__(256) void scanA_kernel(const unsigned* __restrict__ cnt,
                                                    unsigned* __restrict__ bsum, int N) {
    __shared__ unsigned wsum[4];
    int tid = threadIdx.x, wid = tid >> 6, lane = tid & 63;
    int base = blockIdx.x * SCAN_CHUNK + tid * 8;
    unsigned s = 0;
    if (base < N) {
        uint4 a = *(const uint4*)(cnt + base);
        uint4 b = *(const uint4*)(cnt + base + 4);
        s = a.x + a.y + a.z + a.w + b.x + b.y + b.z + b.w;
    }
    #pragma unroll
    for (int off = 32; off >= 1; off >>= 1) s += __shfl_down(s, off, 64);
    if (lane == 0) wsum[wid] = s;
    __syncthreads();
    if (tid == 0) bsum[blockIdx.x] = wsum[0] + wsum[1] + wsum[2] + wsum[3];
}

__global__ __launch_bounds__(64) void scanB_kernel(const unsigned* __restrict__ bsum,
                                                   unsigned* __restrict__ boff,
                                                   unsigned* __restrict__ rowptr_last) {
    int lane = threadIdx.x;
    unsigned v = (lane < SCAN_NB) ? bsum[lane] : 0u;
    unsigned incl = v;
    #pragma unroll
    for (int off = 1; off < 64; off <<= 1) {
        unsigned t = __shfl_up(incl, off, 64);
        if (lane >= off) incl += t;
    }
    if (lane < SCAN_NB) boff[lane] = incl - v;
    if (lane == 63) *rowptr_last = incl;
}

// scanC also emits dinv (it already holds every cnt value in registers)
__global__ __launch_bounds__(256) void scanC_kernel(const unsigned* __restrict__ cnt,
                                                    const unsigned* __restrict__ boff,
                                                    unsigned* __restrict__ rowptr,
                                                    unsigned* __restrict__ cursor,
                                                    float* __restrict__ dinv, int N) {
    __shared__ unsigned wsum[4];
    int tid = threadIdx.x, wid = tid >> 6, lane = tid & 63;
    int base = blockIdx.x * SCAN_CHUNK + tid * 8;
    unsigned v[8];
    unsigned s = 0;
    bool act = base < N;
    if (act) {
        uint4 a = *(const uint4*)(cnt + base);
        uint4 b = *(const uint4*)(cnt + base + 4);
        v[0] = a.x; v[1] = a.y; v[2] = a.z; v[3] = a.w;
        v[4] = b.x; v[5] = b.y; v[6] = b.z; v[7] = b.w;
        #pragma unroll
        for (int j = 0; j < 8; ++j) s += v[j];
    }
    unsigned incl = s;
    #pragma unroll
    for (int off = 1; off < 64; off <<= 1) {
        unsigned t = __shfl_up(incl, off, 64);
        if (lane >= off) incl += t;
    }
    if (lane == 63) wsum[wid] = incl;
    __syncthreads();
    unsigned woff = 0;
    for (int w = 0; w < 4; ++w) if (w < wid) woff += wsum[w];
    if (act) {
        unsigned run = incl - s + woff + boff[blockIdx.x];
        float dv[8];
        #pragma unroll
        for (int j = 0; j < 8; ++j) dv[j] = rsqrtf((float)v[j] + 1.0f);
        #pragma unroll
        for (int j = 0; j < 8; ++j) {
            rowptr[base + j] = run;
            cursor[base + j] = run;
            run += v[j];
        }
        *(float4*)(dinv + base)     = make_float4(dv[0], dv[1], dv[2], dv[3]);
        *(float4*)(dinv + base + 4) = make_float4(dv[4], dv[5], dv[6], dv[7]);
    }
}

// ---------------- CSR fill: 4-byte payload (src only; norm computed in aggregate) ----------------
__global__ __launch_bounds__(256) void fill_kernel(const int* __restrict__ src,
                                                   const int* __restrict__ dst,
                                                   unsigned* __restrict__ cursor,
                                                   unsigned* __restrict__ csr_src, int E) {
    int e = blockIdx.x * 256 + threadIdx.x;
    if (e < E) {
        int d = dst[e];
        unsigned pos = atomicAdd(&cursor[d], 1u);
        csr_src[pos] = (unsigned)src[e];
    }
}

// ---------------- W -> lane-ordered bf16 MFMA fragments ----------------
__global__ __launch_bounds__(256) void wprep_kernel(const float* __restrict__ Ws,
                                                    short* __restrict__ Wf) {
    int l = blockIdx.x;
    for (int idx = threadIdx.x; idx < 16384; idx += 256) {
        int i = idx & 7;
        int lane = (idx >> 3) & 63;
        int ns = idx >> 9;
        int s = ns & 3, nt = ns >> 2;
        int k = s * 32 + (lane >> 4) * 8 + i;
        int n = nt * 16 + (lane & 15);
        Wf[l * 16384 + idx] = (short)f2bf(Ws[l * 16384 + k * NF + n]);
    }
}

// ---------------- H = X @ W via bf16 MFMA; output bf16 ----------------
template<bool L0>
__global__ __launch_bounds__(256) void gemm_mfma_kernel(const void* __restrict__ Xin,
                                                        const short* __restrict__ Wf,
                                                        ushort* __restrict__ Hb, int M) {
    __shared__ short Wl[16384];
    int tid = threadIdx.x;
    for (int i = tid; i < 2048; i += 256)
        ((float4*)Wl)[i] = ((const float4*)Wf)[i];

    int wave = tid >> 6, lane = tid & 63;
    int r = lane & 15, kg = lane >> 4;
    int rowbase = blockIdx.x * 128 + wave * 32;

    bf16x8 afrag[2][4];
    #pragma unroll
    for (int t = 0; t < 2; ++t) {
        #pragma unroll
        for (int s = 0; s < 4; ++s) {
            int row = rowbase + t * 16 + r;
            if (row > M - 1) row = M - 1;
            if (L0) {
                const float* p = (const float*)Xin + (size_t)row * NF + s * 32 + kg * 8;
                float4 u0 = *(const float4*)p;
                float4 u1 = *(const float4*)(p + 4);
                bf16x8 a;
                a[0] = (short)f2bf(u0.x); a[1] = (short)f2bf(u0.y);
                a[2] = (short)f2bf(u0.z); a[3] = (short)f2bf(u0.w);
                a[4] = (short)f2bf(u1.x); a[5] = (short)f2bf(u1.y);
                a[6] = (short)f2bf(u1.z); a[7] = (short)f2bf(u1.w);
                afrag[t][s] = a;
            } else {
                afrag[t][s] = *(const bf16x8*)((const ushort*)Xin + (size_t)row * NF + s * 32 + kg * 8);
            }
        }
    }

    f32x4 acc[2][8];
    #pragma unroll
    for (int t = 0; t < 2; ++t)
        #pragma unroll
        for (int n = 0; n < 8; ++n)
            acc[t][n] = (f32x4){0.f, 0.f, 0.f, 0.f};

    __syncthreads();
    const bf16x8* WL = (const bf16x8*)Wl;
    #pragma unroll
    for (int s = 0; s < 4; ++s) {
        #pragma unroll
        for (int n = 0; n < 8; ++n) {
            bf16x8 bfr = WL[(n * 4 + s) * 64 + lane];
            acc[0][n] = __builtin_amdgcn_mfma_f32_16x16x32_bf16(afrag[0][s], bfr, acc[0][n], 0, 0, 0);
            acc[1][n] = __builtin_amdgcn_mfma_f32_16x16x32_bf16(afrag[1][s], bfr, acc[1][n], 0, 0, 0);
        }
    }

    int r4 = kg * 4;
    #pragma unroll
    for (int t = 0; t < 2; ++t) {
        #pragma unroll
        for (int n = 0; n < 8; ++n) {
            #pragma unroll
            for (int q = 0; q < 4; ++q) {
                int row = rowbase + t * 16 + r4 + q;
                if (row < M) Hb[(size_t)row * NF + n * 16 + r] = f2bf(acc[t][n][q]);
            }
        }
    }
}

// ---------------- aggregate: bf16 gather, norm from dinv, fp32 math, bf16 out ----------------
__global__ __launch_bounds__(256) void aggregate_kernel(const ushort* __restrict__ Hb,
                                                        const float* __restrict__ dinv,
                                                        const unsigned* __restrict__ rowptr,
                                                        const unsigned* __restrict__ csr_src,
                                                        const float* __restrict__ bias,
                                                        ushort* __restrict__ Xout, int N) {
    int gid = blockIdx.x * 256 + threadIdx.x;
    int node = gid >> 5;
    int lane = gid & 31;
    if (node >= N) return;
    float di = dinv[node];
    float sl = di * di;
    float4 b = ((const float4*)bias)[lane];
    ushort4 hv = *(const ushort4*)(Hb + (size_t)node * NF + lane * 4);
    float ax = fmaf(b2f(hv.x), sl, b.x);
    float ay = fmaf(b2f(hv.y), sl, b.y);
    float az = fmaf(b2f(hv.z), sl, b.z);
    float aw = fmaf(b2f(hv.w), sl, b.w);
    unsigned e = rowptr[node], end = rowptr[node + 1];
    for (; e + 4 <= end; e += 4) {
        unsigned s0 = csr_src[e + 0], s1 = csr_src[e + 1];
        unsigned s2 = csr_src[e + 2], s3 = csr_src[e + 3];
        float n0 = dinv[s0] * di, n1 = dinv[s1] * di;
        float n2 = dinv[s2] * di, n3 = dinv[s3] * di;
        ushort4 g0 = *(const ushort4*)(Hb + (size_t)s0 * NF + lane * 4);
        ushort4 g1 = *(const ushort4*)(Hb + (size_t)s1 * NF + lane * 4);
        ushort4 g2 = *(const ushort4*)(Hb + (size_t)s2 * NF + lane * 4);
        ushort4 g3 = *(const ushort4*)(Hb + (size_t)s3 * NF + lane * 4);
        ax = fmaf(b2f(g0.x), n0, ax); ay = fmaf(b2f(g0.y), n0, ay);
        az = fmaf(b2f(g0.z), n0, az); aw = fmaf(b2f(g0.w), n0, aw);
        ax = fmaf(b2f(g1.x), n1, ax); ay = fmaf(b2f(g1.y), n1, ay);
        az = fmaf(b2f(g1.z), n1, az); aw = fmaf(b2f(g1.w), n1, aw);
        ax = fmaf(b2f(g2.x), n2, ax); ay = fmaf(b2f(g2.y), n2, ay);
        az = fmaf(b2f(g2.z), n2, az); aw = fmaf(b2f(g2.w), n2, aw);
        ax = fmaf(b2f(g3.x), n3, ax); ay = fmaf(b2f(g3.y), n3, ay);
        az = fmaf(b2f(g3.z), n3, az); aw = fmaf(b2f(g3.w), n3, aw);
    }
    for (; e < end; ++e) {
        unsigned s = csr_src[e];
        float nm = dinv[s] * di;
        ushort4 g = *(const ushort4*)(Hb + (size_t)s * NF + lane * 4);
        ax = fmaf(b2f(g.x), nm, ax); ay = fmaf(b2f(g.y), nm, ay);
        az = fmaf(b2f(g.z), nm, az); aw = fmaf(b2f(g.w), nm, aw);
    }
    ax = ax > 0.f ? ax : expm1f(ax);
    ay = ay > 0.f ? ay : expm1f(ay);
    az = az > 0.f ? az : expm1f(az);
    aw = aw > 0.f ? aw : expm1f(aw);
    ushort4 o;
    o.x = f2bf(ax); o.y = f2bf(ay); o.z = f2bf(az); o.w = f2bf(aw);
    *(ushort4*)(Xout + (size_t)node * NF + lane * 4) = o;
}

// ---------------- global max pool: node-parallel, atomicMax on monotone enc ----------------
__global__ __launch_bounds__(256) void pool_kernel(const ushort* __restrict__ X,
                                                   const int* __restrict__ batch,
                                                   unsigned* __restrict__ Gx, int N) {
    __shared__ int gb[256];
    int n0 = blockIdx.x * 256;
    int tid = threadIdx.x;
    {
        int n = n0 + tid;
        gb[tid] = (n < N) ? batch[n] : -1;
    }
    __syncthreads();
    int cg = tid & 31;
    int rg = tid >> 5;
    float mx = -FLT_MAX, my = -FLT_MAX, mz = -FLT_MAX, mw = -FLT_MAX;
    int curg = -1;
    for (int i = rg; i < 256; i += 8) {
        int n = n0 + i;
        if (n >= N) break;
        int g = gb[i];
        if (g != curg) {
            if (curg >= 0) {
                unsigned* p = Gx + (size_t)curg * NF + cg * 4;
                atomicMax(p + 0, fenc(mx)); atomicMax(p + 1, fenc(my));
                atomicMax(p + 2, fenc(mz)); atomicMax(p + 3, fenc(mw));
            }
            curg = g;
            mx = my = mz = mw = -FLT_MAX;
        }
        ushort4 v = *(const ushort4*)(X + (size_t)n * NF + cg * 4);
        mx = fmaxf(mx, b2f(v.x)); my = fmaxf(my, b2f(v.y));
        mz = fmaxf(mz, b2f(v.z)); mw = fmaxf(mw, b2f(v.w));
    }
    if (curg >= 0) {
        unsigned* p = Gx + (size_t)curg * NF + cg * 4;
        atomicMax(p + 0, fenc(mx)); atomicMax(p + 1, fenc(my));
        atomicMax(p + 2, fenc(mz)); atomicMax(p + 3, fenc(mw));
    }
}

// ---------------- classifier: softmax(decode(Gx) @ Wc + bc), fp32 ----------------
__global__ __launch_bounds__(128) void classify_kernel(const unsigned* __restrict__ Gx,
                                                       const float* __restrict__ Wc,
                                                       const float* __restrict__ bc,
                                                       float* __restrict__ out) {
    __shared__ float gr[NF];
    __shared__ float lg[NCLASSES];
    int g = blockIdx.x;
    int tid = threadIdx.x;
    gr[tid] = fdec(Gx[(size_t)g * NF + tid]);
    __syncthreads();
    if (tid < NCLASSES) {
        float s = bc[tid];
        for (int k = 0; k < NF; ++k) s = fmaf(gr[k], Wc[k * NCLASSES + tid], s);
        lg[tid] = s;
    }
    __syncthreads();
    if (tid == 0) {
        float m = lg[0];
        #pragma unroll
        for (int c = 1; c < NCLASSES; ++c) m = fmaxf(m, lg[c]);
        float e[NCLASSES];
        float sum = 0.f;
        #pragma unroll
        for (int c = 0; c < NCLASSES; ++c) { e[c] = expf(lg[c] - m); sum += e[c]; }
        #pragma unroll
        for (int c = 0; c < NCLASSES; ++c) out[g * NCLASSES + c] = e[c] / sum;
    }
}

extern "C" void kernel_launch(void* const* d_in, const int* in_sizes, int n_in,
                              void* d_out, int out_size, void* d_ws, size_t ws_size,
                              hipStream_t stream) {
    const float* x     = (const float*)d_in[0];
    const int*   ei    = (const int*)d_in[1];
    const int*   batch = (const int*)d_in[2];
    const float* Ws    = (const float*)d_in[3];
    const float* bs    = (const float*)d_in[4];
    const float* Wc    = (const float*)d_in[5];
    const float* bc    = (const float*)d_in[6];
    float* out = (float*)d_out;

    const int* src = ei;
    const int* dst = ei + NEDGES;

    char* ws = (char*)d_ws;
    size_t off = 0;
    auto alloc = [&](size_t bytes) -> void* {
        off = (off + 255) & ~(size_t)255;
        void* p = ws + off;
        off += bytes;
        return p;
    };
    ushort*   B0      = (ushort*)alloc(sizeof(ushort) * (size_t)NNODES * NF);
    ushort*   B1      = (ushort*)alloc(sizeof(ushort) * (size_t)NNODES * NF);
    ushort*   Hb      = (ushort*)alloc(sizeof(ushort) * (size_t)NNODES * NF);
    float*    dinvp   = (float*)alloc(sizeof(float) * NNODES);
    unsigned* cursor  = (unsigned*)alloc(sizeof(unsigned) * NNODES);
    unsigned* rowptr  = (unsigned*)alloc(sizeof(unsigned) * (NNODES + 1));
    unsigned* csr_src = (unsigned*)alloc(sizeof(unsigned) * NEDGES);
    unsigned* bsum    = (unsigned*)alloc(sizeof(unsigned) * SCAN_NB);
    unsigned* boff    = (unsigned*)alloc(sizeof(unsigned) * SCAN_NB);
    short*    Wf      = (short*)alloc(sizeof(short) * 3 * 16384);
    // zero-region: cnt + Gx contiguous -> single memset
    unsigned* cnt     = (unsigned*)alloc(sizeof(unsigned) * NNODES);
    unsigned* Gx      = (unsigned*)alloc(sizeof(unsigned) * NGRAPHS * NF);
    size_t zspan = (size_t)((char*)(Gx + NGRAPHS * NF) - (char*)cnt);

    hipMemsetAsync(cnt, 0, zspan, stream);
    wprep_kernel<<<3, 256, 0, stream>>>(Ws, Wf);
    hist_kernel<<<(NEDGES + 255) / 256, 256, 0, stream>>>(dst, cnt, NEDGES);
    scanA_kernel<<<SCAN_NB, 256, 0, stream>>>(cnt, bsum, NNODES);
    scanB_kernel<<<1, 64, 0, stream>>>(bsum, boff, rowptr + NNODES);
    scanC_kernel<<<SCAN_NB, 256, 0, stream>>>(cnt, boff, rowptr, cursor, dinvp, NNODES);
    fill_kernel<<<(NEDGES + 255) / 256, 256, 0, stream>>>(src, dst, cursor, csr_src, NEDGES);

    int gemm_grid = (NNODES + 127) / 128;   // 782
    int agg_grid  = (NNODES * 32) / 256;    // 12500 exact

    gemm_mfma_kernel<true><<<gemm_grid, 256, 0, stream>>>(x, Wf + 0 * 16384, Hb, NNODES);
    aggregate_kernel<<<agg_grid, 256, 0, stream>>>(Hb, dinvp, rowptr, csr_src, bs + 0 * NF, B1, NNODES);
    gemm_mfma_kernel<false><<<gemm_grid, 256, 0, stream>>>(B1, Wf + 1 * 16384, Hb, NNODES);
    aggregate_kernel<<<agg_grid, 256, 0, stream>>>(Hb, dinvp, rowptr, csr_src, bs + 1 * NF, B0, NNODES);
    gemm_mfma_kernel<false><<<gemm_grid, 256, 0, stream>>>(B0, Wf + 2 * 16384, Hb, NNODES);
    aggregate_kernel<<<agg_grid, 256, 0, stream>>>(Hb, dinvp, rowptr, csr_src, bs + 2 * NF, B1, NNODES);

    pool_kernel<<<(NNODES + 255) / 256, 256, 0, stream>>>(B1, batch, Gx, NNODES);
    classify_kernel<<<NGRAPHS, 128, 0, stream>>>(Gx, Wc, bc, out);
}

// Round 7
// 267.457 us; speedup vs baseline: 1.4935x; 1.1978x over previous
//
#include <hip/hip_runtime.h>
#include <float.h>
#include <math.h>

#define NNODES 100000
#define NEDGES 800000
#define NF 128
#define NCLASSES 10
#define NGRAPHS 256

#define NBIN 98              // ceil(100000 / 1024) dst-bins of 1024 nodes
#define BCHUNK 4096          // edges per block in binct/binscatter
#define NB2 196              // ceil(NEDGES / BCHUNK)
#define CNTS_PAD 20480       // NBIN*NB2 = 19208, padded to 10*2048 for the scan
#define SCAN_CHUNK 2048

typedef __attribute__((ext_vector_type(8))) short bf16x8;
typedef __attribute__((ext_vector_type(4))) float f32x4;

__device__ inline ushort f2bf(float f) {  // fp32 -> bf16 RNE
    unsigned u = __float_as_uint(f);
    u = u + 0x7FFFu + ((u >> 16) & 1u);
    return (ushort)(u >> 16);
}
__device__ inline float b2f(ushort h) {
    return __uint_as_float(((unsigned)h) << 16);
}
// monotone fp32<->uint encoding: uint max order == float max order
__device__ inline unsigned fenc(float f) {
    unsigned u = __float_as_uint(f);
    return ((int)u < 0) ? ~u : (u | 0x80000000u);
}
__device__ inline float fdec(unsigned s) {
    return (s & 0x80000000u) ? __uint_as_float(s ^ 0x80000000u) : __uint_as_float(~s);
}

// ---------------- pass 1: per-(bin, block) edge counts ----------------
__global__ __launch_bounds__(256) void binct_kernel(const int* __restrict__ dst,
                                                    unsigned* __restrict__ cnts, int E) {
    __shared__ unsigned lh[NBIN];
    int tid = threadIdx.x;
    if (tid < NBIN) lh[tid] = 0;
    __syncthreads();
    int e0 = blockIdx.x * BCHUNK;
    int e1 = min(e0 + BCHUNK, E);
    for (int e = e0 + tid; e < e1; e += 256)
        atomicAdd(&lh[dst[e] >> 10], 1u);
    __syncthreads();
    if (tid < NBIN) cnts[tid * NB2 + blockIdx.x] = lh[tid];
}

// ---------------- small multi-block exclusive scan (N = CNTS_PAD) ----------------
__global__ __launch_bounds__(256) void scanA_kernel(const unsigned* __restrict__ cnt,
                                                    unsigned* __restrict__ bsum, int N) {
    __shared__ unsigned wsum[4];
    int tid = threadIdx.x, wid = tid >> 6, lane = tid & 63;
    int base = blockIdx.x * SCAN_CHUNK + tid * 8;
    unsigned s = 0;
    if (base < N) {
        uint4 a = *(const uint4*)(cnt + base);
        uint4 b = *(const uint4*)(cnt + base + 4);
        s = a.x + a.y + a.z + a.w + b.x + b.y + b.z + b.w;
    }
    #pragma unroll
    for (int off = 32; off >= 1; off >>= 1) s += __shfl_down(s, off, 64);
    if (lane == 0) wsum[wid] = s;
    __syncthreads();
    if (tid == 0) bsum[blockIdx.x] = wsum[0] + wsum[1] + wsum[2] + wsum[3];
}

__global__ __launch_bounds__(64) void scanB_kernel(const unsigned* __restrict__ bsum,
                                                   unsigned* __restrict__ boff, int nb) {
    int lane = threadIdx.x;
    unsigned v = (lane < nb) ? bsum[lane] : 0u;
    unsigned incl = v;
    #pragma unroll
    for (int off = 1; off < 64; off <<= 1) {
        unsigned t = __shfl_up(incl, off, 64);
        if (lane >= off) incl += t;
    }
    if (lane < nb) boff[lane] = incl - v;
}

__global__ __launch_bounds__(256) void scanC_kernel(const unsigned* __restrict__ cnt,
                                                    const unsigned* __restrict__ boff,
                                                    unsigned* __restrict__ outp, int N) {
    __shared__ unsigned wsum[4];
    int tid = threadIdx.x, wid = tid >> 6, lane = tid & 63;
    int base = blockIdx.x * SCAN_CHUNK + tid * 8;
    unsigned v[8];
    unsigned s = 0;
    bool act = base < N;
    if (act) {
        uint4 a = *(const uint4*)(cnt + base);
        uint4 b = *(const uint4*)(cnt + base + 4);
        v[0] = a.x; v[1] = a.y; v[2] = a.z; v[3] = a.w;
        v[4] = b.x; v[5] = b.y; v[6] = b.z; v[7] = b.w;
        #pragma unroll
        for (int j = 0; j < 8; ++j) s += v[j];
    }
    unsigned incl = s;
    #pragma unroll
    for (int off = 1; off < 64; off <<= 1) {
        unsigned t = __shfl_up(incl, off, 64);
        if (lane >= off) incl += t;
    }
    if (lane == 63) wsum[wid] = incl;
    __syncthreads();
    unsigned woff = 0;
    for (int w = 0; w < 4; ++w) if (w < wid) woff += wsum[w];
    if (act) {
        unsigned run = incl - s + woff + boff[blockIdx.x];
        #pragma unroll
        for (int j = 0; j < 8; ++j) {
            outp[base + j] = run;
            run += v[j];
        }
    }
}

// ---------------- pass 3: scatter edges bin-contiguously (LDS cursors, no global atomics) ----------------
__global__ __launch_bounds__(256) void binscatter_kernel(const int* __restrict__ src,
                                                         const int* __restrict__ dst,
                                                         const unsigned* __restrict__ offs,
                                                         unsigned* __restrict__ bedge, int E) {
    __shared__ unsigned lcur[NBIN];
    int tid = threadIdx.x;
    if (tid < NBIN) lcur[tid] = offs[tid * NB2 + blockIdx.x];
    __syncthreads();
    int e0 = blockIdx.x * BCHUNK;
    int e1 = min(e0 + BCHUNK, E);
    for (int e = e0 + tid; e < e1; e += 256) {
        int d = dst[e];
        int b = d >> 10;
        unsigned pos = atomicAdd(&lcur[b], 1u);
        bedge[pos] = ((unsigned)src[e] << 10) | (unsigned)(d & 1023);
    }
}

// ---------------- pass 4: per-bin node counts -> rowptr, dinv, csr placement ----------------
__global__ __launch_bounds__(256) void bucket_kernel(const unsigned* __restrict__ bedge,
                                                     const unsigned* __restrict__ offs,
                                                     float* __restrict__ dinv,
                                                     unsigned* __restrict__ rowptr,
                                                     unsigned* __restrict__ csr_src, int N) {
    __shared__ unsigned lcnt[1024];
    __shared__ unsigned lcur[1024];
    __shared__ unsigned wsum[4];
    int b = blockIdx.x;
    int tid = threadIdx.x, wid = tid >> 6, lane = tid & 63;
    unsigned ebeg = offs[b * NB2], eend = offs[(b + 1) * NB2];
    lcnt[tid] = 0; lcnt[tid + 256] = 0; lcnt[tid + 512] = 0; lcnt[tid + 768] = 0;
    __syncthreads();
    for (unsigned e = ebeg + tid; e < eend; e += 256)
        atomicAdd(&lcnt[bedge[e] & 1023], 1u);
    __syncthreads();
    // in-block exclusive scan of 1024 counts (256 thr x 4)
    unsigned c[4];
    unsigned s = 0;
    #pragma unroll
    for (int j = 0; j < 4; ++j) { c[j] = lcnt[tid * 4 + j]; s += c[j]; }
    unsigned incl = s;
    #pragma unroll
    for (int off = 1; off < 64; off <<= 1) {
        unsigned t = __shfl_up(incl, off, 64);
        if (lane >= off) incl += t;
    }
    if (lane == 63) wsum[wid] = incl;
    __syncthreads();
    unsigned woff = 0;
    for (int w = 0; w < 4; ++w) if (w < wid) woff += wsum[w];
    unsigned run = (incl - s) + woff + ebeg;
    int gbase = b * 1024 + tid * 4;
    #pragma unroll
    for (int j = 0; j < 4; ++j) {
        if (gbase + j < N) {
            rowptr[gbase + j] = run;
            dinv[gbase + j] = rsqrtf((float)c[j] + 1.0f);
        }
        lcur[tid * 4 + j] = run;
        run += c[j];
    }
    if (b == NBIN - 1 && tid == 0) rowptr[N] = eend;
    __syncthreads();
    for (unsigned e = ebeg + tid; e < eend; e += 256) {
        unsigned v = bedge[e];
        unsigned pos = atomicAdd(&lcur[v & 1023], 1u);
        csr_src[pos] = v >> 10;
    }
}

// ---------------- W -> lane-ordered bf16 MFMA fragments ----------------
__global__ __launch_bounds__(256) void wprep_kernel(const float* __restrict__ Ws,
                                                    short* __restrict__ Wf) {
    int l = blockIdx.x;
    for (int idx = threadIdx.x; idx < 16384; idx += 256) {
        int i = idx & 7;
        int lane = (idx >> 3) & 63;
        int ns = idx >> 9;
        int s = ns & 3, nt = ns >> 2;
        int k = s * 32 + (lane >> 4) * 8 + i;
        int n = nt * 16 + (lane & 15);
        Wf[l * 16384 + idx] = (short)f2bf(Ws[l * 16384 + k * NF + n]);
    }
}

// ---------------- H = X @ W via bf16 MFMA; output bf16 ----------------
template<bool L0>
__global__ __launch_bounds__(256) void gemm_mfma_kernel(const void* __restrict__ Xin,
                                                        const short* __restrict__ Wf,
                                                        ushort* __restrict__ Hb, int M) {
    __shared__ short Wl[16384];
    int tid = threadIdx.x;
    for (int i = tid; i < 2048; i += 256)
        ((float4*)Wl)[i] = ((const float4*)Wf)[i];

    int wave = tid >> 6, lane = tid & 63;
    int r = lane & 15, kg = lane >> 4;
    int rowbase = blockIdx.x * 128 + wave * 32;

    bf16x8 afrag[2][4];
    #pragma unroll
    for (int t = 0; t < 2; ++t) {
        #pragma unroll
        for (int s = 0; s < 4; ++s) {
            int row = rowbase + t * 16 + r;
            if (row > M - 1) row = M - 1;
            if (L0) {
                const float* p = (const float*)Xin + (size_t)row * NF + s * 32 + kg * 8;
                float4 u0 = *(const float4*)p;
                float4 u1 = *(const float4*)(p + 4);
                bf16x8 a;
                a[0] = (short)f2bf(u0.x); a[1] = (short)f2bf(u0.y);
                a[2] = (short)f2bf(u0.z); a[3] = (short)f2bf(u0.w);
                a[4] = (short)f2bf(u1.x); a[5] = (short)f2bf(u1.y);
                a[6] = (short)f2bf(u1.z); a[7] = (short)f2bf(u1.w);
                afrag[t][s] = a;
            } else {
                afrag[t][s] = *(const bf16x8*)((const ushort*)Xin + (size_t)row * NF + s * 32 + kg * 8);
            }
        }
    }

    f32x4 acc[2][8];
    #pragma unroll
    for (int t = 0; t < 2; ++t)
        #pragma unroll
        for (int n = 0; n < 8; ++n)
            acc[t][n] = (f32x4){0.f, 0.f, 0.f, 0.f};

    __syncthreads();
    const bf16x8* WL = (const bf16x8*)Wl;
    #pragma unroll
    for (int s = 0; s < 4; ++s) {
        #pragma unroll
        for (int n = 0; n < 8; ++n) {
            bf16x8 bfr = WL[(n * 4 + s) * 64 + lane];
            acc[0][n] = __builtin_amdgcn_mfma_f32_16x16x32_bf16(afrag[0][s], bfr, acc[0][n], 0, 0, 0);
            acc[1][n] = __builtin_amdgcn_mfma_f32_16x16x32_bf16(afrag[1][s], bfr, acc[1][n], 0, 0, 0);
        }
    }

    int r4 = kg * 4;
    #pragma unroll
    for (int t = 0; t < 2; ++t) {
        #pragma unroll
        for (int n = 0; n < 8; ++n) {
            #pragma unroll
            for (int q = 0; q < 4; ++q) {
                int row = rowbase + t * 16 + r4 + q;
                if (row < M) Hb[(size_t)row * NF + n * 16 + r] = f2bf(acc[t][n][q]);
            }
        }
    }
}

// ---------------- aggregate: bf16 gather, norm from dinv, fp32 math, bf16 out ----------------
__global__ __launch_bounds__(256) void aggregate_kernel(const ushort* __restrict__ Hb,
                                                        const float* __restrict__ dinv,
                                                        const unsigned* __restrict__ rowptr,
                                                        const unsigned* __restrict__ csr_src,
                                                        const float* __restrict__ bias,
                                                        ushort* __restrict__ Xout, int N) {
    int gid = blockIdx.x * 256 + threadIdx.x;
    int node = gid >> 5;
    int lane = gid & 31;
    if (node >= N) return;
    float di = dinv[node];
    float sl = di * di;
    float4 b = ((const float4*)bias)[lane];
    ushort4 hv = *(const ushort4*)(Hb + (size_t)node * NF + lane * 4);
    float ax = fmaf(b2f(hv.x), sl, b.x);
    float ay = fmaf(b2f(hv.y), sl, b.y);
    float az = fmaf(b2f(hv.z), sl, b.z);
    float aw = fmaf(b2f(hv.w), sl, b.w);
    unsigned e = rowptr[node], end = rowptr[node + 1];
    for (; e + 4 <= end; e += 4) {
        unsigned s0 = csr_src[e + 0], s1 = csr_src[e + 1];
        unsigned s2 = csr_src[e + 2], s3 = csr_src[e + 3];
        float n0 = dinv[s0] * di, n1 = dinv[s1] * di;
        float n2 = dinv[s2] * di, n3 = dinv[s3] * di;
        ushort4 g0 = *(const ushort4*)(Hb + (size_t)s0 * NF + lane * 4);
        ushort4 g1 = *(const ushort4*)(Hb + (size_t)s1 * NF + lane * 4);
        ushort4 g2 = *(const ushort4*)(Hb + (size_t)s2 * NF + lane * 4);
        ushort4 g3 = *(const ushort4*)(Hb + (size_t)s3 * NF + lane * 4);
        ax = fmaf(b2f(g0.x), n0, ax); ay = fmaf(b2f(g0.y), n0, ay);
        az = fmaf(b2f(g0.z), n0, az); aw = fmaf(b2f(g0.w), n0, aw);
        ax = fmaf(b2f(g1.x), n1, ax); ay = fmaf(b2f(g1.y), n1, ay);
        az = fmaf(b2f(g1.z), n1, az); aw = fmaf(b2f(g1.w), n1, aw);
        ax = fmaf(b2f(g2.x), n2, ax); ay = fmaf(b2f(g2.y), n2, ay);
        az = fmaf(b2f(g2.z), n2, az); aw = fmaf(b2f(g2.w), n2, aw);
        ax = fmaf(b2f(g3.x), n3, ax); ay = fmaf(b2f(g3.y), n3, ay);
        az = fmaf(b2f(g3.z), n3, az); aw = fmaf(b2f(g3.w), n3, aw);
    }
    for (; e < end; ++e) {
        unsigned s = csr_src[e];
        float nm = dinv[s] * di;
        ushort4 g = *(const ushort4*)(Hb + (size_t)s * NF + lane * 4);
        ax = fmaf(b2f(g.x), nm, ax); ay = fmaf(b2f(g.y), nm, ay);
        az = fmaf(b2f(g.z), nm, az); aw = fmaf(b2f(g.w), nm, aw);
    }
    ax = ax > 0.f ? ax : expm1f(ax);
    ay = ay > 0.f ? ay : expm1f(ay);
    az = az > 0.f ? az : expm1f(az);
    aw = aw > 0.f ? aw : expm1f(aw);
    ushort4 o;
    o.x = f2bf(ax); o.y = f2bf(ay); o.z = f2bf(az); o.w = f2bf(aw);
    *(ushort4*)(Xout + (size_t)node * NF + lane * 4) = o;
}

// ---------------- global max pool: node-parallel, atomicMax on monotone enc ----------------
__global__ __launch_bounds__(256) void pool_kernel(const ushort* __restrict__ X,
                                                   const int* __restrict__ batch,
                                                   unsigned* __restrict__ Gx, int N) {
    __shared__ int gb[256];
    int n0 = blockIdx.x * 256;
    int tid = threadIdx.x;
    {
        int n = n0 + tid;
        gb[tid] = (n < N) ? batch[n] : -1;
    }
    __syncthreads();
    int cg = tid & 31;
    int rg = tid >> 5;
    float mx = -FLT_MAX, my = -FLT_MAX, mz = -FLT_MAX, mw = -FLT_MAX;
    int curg = -1;
    for (int i = rg; i < 256; i += 8) {
        int n = n0 + i;
        if (n >= N) break;
        int g = gb[i];
        if (g != curg) {
            if (curg >= 0) {
                unsigned* p = Gx + (size_t)curg * NF + cg * 4;
                atomicMax(p + 0, fenc(mx)); atomicMax(p + 1, fenc(my));
                atomicMax(p + 2, fenc(mz)); atomicMax(p + 3, fenc(mw));
            }
            curg = g;
            mx = my = mz = mw = -FLT_MAX;
        }
        ushort4 v = *(const ushort4*)(X + (size_t)n * NF + cg * 4);
        mx = fmaxf(mx, b2f(v.x)); my = fmaxf(my, b2f(v.y));
        mz = fmaxf(mz, b2f(v.z)); mw = fmaxf(mw, b2f(v.w));
    }
    if (curg >= 0) {
        unsigned* p = Gx + (size_t)curg * NF + cg * 4;
        atomicMax(p + 0, fenc(mx)); atomicMax(p + 1, fenc(my));
        atomicMax(p + 2, fenc(mz)); atomicMax(p + 3, fenc(mw));
    }
}

// ---------------- classifier: softmax(decode(Gx) @ Wc + bc), fp32 ----------------
__global__ __launch_bounds__(128) void classify_kernel(const unsigned* __restrict__ Gx,
                                                       const float* __restrict__ Wc,
                                                       const float* __restrict__ bc,
                                                       float* __restrict__ out) {
    __shared__ float gr[NF];
    __shared__ float lg[NCLASSES];
    int g = blockIdx.x;
    int tid = threadIdx.x;
    gr[tid] = fdec(Gx[(size_t)g * NF + tid]);
    __syncthreads();
    if (tid < NCLASSES) {
        float s = bc[tid];
        for (int k = 0; k < NF; ++k) s = fmaf(gr[k], Wc[k * NCLASSES + tid], s);
        lg[tid] = s;
    }
    __syncthreads();
    if (tid == 0) {
        float m = lg[0];
        #pragma unroll
        for (int c = 1; c < NCLASSES; ++c) m = fmaxf(m, lg[c]);
        float e[NCLASSES];
        float sum = 0.f;
        #pragma unroll
        for (int c = 0; c < NCLASSES; ++c) { e[c] = expf(lg[c] - m); sum += e[c]; }
        #pragma unroll
        for (int c = 0; c < NCLASSES; ++c) out[g * NCLASSES + c] = e[c] / sum;
    }
}

extern "C" void kernel_launch(void* const* d_in, const int* in_sizes, int n_in,
                              void* d_out, int out_size, void* d_ws, size_t ws_size,
                              hipStream_t stream) {
    const float* x     = (const float*)d_in[0];
    const int*   ei    = (const int*)d_in[1];
    const int*   batch = (const int*)d_in[2];
    const float* Ws    = (const float*)d_in[3];
    const float* bs    = (const float*)d_in[4];
    const float* Wc    = (const float*)d_in[5];
    const float* bc    = (const float*)d_in[6];
    float* out = (float*)d_out;

    const int* src = ei;
    const int* dst = ei + NEDGES;

    char* ws = (char*)d_ws;
    size_t off = 0;
    auto alloc = [&](size_t bytes) -> void* {
        off = (off + 255) & ~(size_t)255;
        void* p = ws + off;
        off += bytes;
        return p;
    };
    ushort*   B0      = (ushort*)alloc(sizeof(ushort) * (size_t)NNODES * NF);
    ushort*   B1      = (ushort*)alloc(sizeof(ushort) * (size_t)NNODES * NF);
    ushort*   Hb      = (ushort*)alloc(sizeof(ushort) * (size_t)NNODES * NF);
    float*    dinvp   = (float*)alloc(sizeof(float) * NNODES);
    unsigned* rowptr  = (unsigned*)alloc(sizeof(unsigned) * (NNODES + 1));
    unsigned* csr_src = (unsigned*)alloc(sizeof(unsigned) * NEDGES);
    unsigned* bedge   = (unsigned*)alloc(sizeof(unsigned) * NEDGES);
    unsigned* offs    = (unsigned*)alloc(sizeof(unsigned) * (CNTS_PAD + 1));
    unsigned* bsum    = (unsigned*)alloc(sizeof(unsigned) * 16);
    unsigned* boff    = (unsigned*)alloc(sizeof(unsigned) * 16);
    short*    Wf      = (short*)alloc(sizeof(short) * 3 * 16384);
    // zero-region: cnts + Gx contiguous -> single memset
    unsigned* cnts    = (unsigned*)alloc(sizeof(unsigned) * CNTS_PAD);
    unsigned* Gx      = (unsigned*)alloc(sizeof(unsigned) * NGRAPHS * NF);
    size_t zspan = (size_t)((char*)(Gx + NGRAPHS * NF) - (char*)cnts);

    hipMemsetAsync(cnts, 0, zspan, stream);
    wprep_kernel<<<3, 256, 0, stream>>>(Ws, Wf);
    binct_kernel<<<NB2, 256, 0, stream>>>(dst, cnts, NEDGES);
    scanA_kernel<<<CNTS_PAD / SCAN_CHUNK, 256, 0, stream>>>(cnts, bsum, CNTS_PAD);
    scanB_kernel<<<1, 64, 0, stream>>>(bsum, boff, CNTS_PAD / SCAN_CHUNK);
    scanC_kernel<<<CNTS_PAD / SCAN_CHUNK, 256, 0, stream>>>(cnts, boff, offs, CNTS_PAD);
    binscatter_kernel<<<NB2, 256, 0, stream>>>(src, dst, offs, bedge, NEDGES);
    bucket_kernel<<<NBIN, 256, 0, stream>>>(bedge, offs, dinvp, rowptr, csr_src, NNODES);

    int gemm_grid = (NNODES + 127) / 128;   // 782
    int agg_grid  = (NNODES * 32) / 256;    // 12500 exact

    gemm_mfma_kernel<true><<<gemm_grid, 256, 0, stream>>>(x, Wf + 0 * 16384, Hb, NNODES);
    aggregate_kernel<<<agg_grid, 256, 0, stream>>>(Hb, dinvp, rowptr, csr_src, bs + 0 * NF, B1, NNODES);
    gemm_mfma_kernel<false><<<gemm_grid, 256, 0, stream>>>(B1, Wf + 1 * 16384, Hb, NNODES);
    aggregate_kernel<<<agg_grid, 256, 0, stream>>>(Hb, dinvp, rowptr, csr_src, bs + 1 * NF, B0, NNODES);
    gemm_mfma_kernel<false><<<gemm_grid, 256, 0, stream>>>(B0, Wf + 2 * 16384, Hb, NNODES);
    aggregate_kernel<<<agg_grid, 256, 0, stream>>>(Hb, dinvp, rowptr, csr_src, bs + 2 * NF, B1, NNODES);

    pool_kernel<<<(NNODES + 255) / 256, 256, 0, stream>>>(B1, batch, Gx, NNODES);
    classify_kernel<<<NGRAPHS, 128, 0, stream>>>(Gx, Wc, bc, out);
}

// Round 8
// 258.673 us; speedup vs baseline: 1.5443x; 1.0340x over previous
//
#include <hip/hip_runtime.h>
#include <float.h>
#include <math.h>

#define NNODES 100000
#define NEDGES 800000
#define NF 128
#define NCLASSES 10
#define NGRAPHS 256

#define NBIN 98              // ceil(100000 / 1024) dst-bins of 1024 nodes
#define BCHUNK 4096          // edges per block in binct/binscatter
#define NB2 196              // ceil(NEDGES / BCHUNK)
#define CNTS_PAD 20480       // NBIN*NB2 = 19208, padded to 10*2048 for the scan
#define SCAN_CHUNK 2048

typedef __attribute__((ext_vector_type(8))) short bf16x8;
typedef __attribute__((ext_vector_type(4))) float f32x4;

__device__ inline ushort f2bf(float f) {  // fp32 -> bf16 RNE
    unsigned u = __float_as_uint(f);
    u = u + 0x7FFFu + ((u >> 16) & 1u);
    return (ushort)(u >> 16);
}
__device__ inline float b2f(ushort h) {
    return __uint_as_float(((unsigned)h) << 16);
}
// monotone fp32<->uint encoding: uint max order == float max order
__device__ inline unsigned fenc(float f) {
    unsigned u = __float_as_uint(f);
    return ((int)u < 0) ? ~u : (u | 0x80000000u);
}
__device__ inline float fdec(unsigned s) {
    return (s & 0x80000000u) ? __uint_as_float(s ^ 0x80000000u) : __uint_as_float(~s);
}

// ---------------- pass 1: per-(bin, block) edge counts ----------------
__global__ __launch_bounds__(256) void binct_kernel(const int* __restrict__ dst,
                                                    unsigned* __restrict__ cnts, int E) {
    __shared__ unsigned lh[NBIN];
    int tid = threadIdx.x;
    if (tid < NBIN) lh[tid] = 0;
    __syncthreads();
    int e0 = blockIdx.x * BCHUNK;
    int e1 = min(e0 + BCHUNK, E);
    for (int e = e0 + tid; e < e1; e += 256)
        atomicAdd(&lh[dst[e] >> 10], 1u);
    __syncthreads();
    if (tid < NBIN) cnts[tid * NB2 + blockIdx.x] = lh[tid];
}

// ---------------- small multi-block exclusive scan (N = CNTS_PAD) ----------------
__global__ __launch_bounds__(256) void scanA_kernel(const unsigned* __restrict__ cnt,
                                                    unsigned* __restrict__ bsum, int N) {
    __shared__ unsigned wsum[4];
    int tid = threadIdx.x, wid = tid >> 6, lane = tid & 63;
    int base = blockIdx.x * SCAN_CHUNK + tid * 8;
    unsigned s = 0;
    if (base < N) {
        uint4 a = *(const uint4*)(cnt + base);
        uint4 b = *(const uint4*)(cnt + base + 4);
        s = a.x + a.y + a.z + a.w + b.x + b.y + b.z + b.w;
    }
    #pragma unroll
    for (int off = 32; off >= 1; off >>= 1) s += __shfl_down(s, off, 64);
    if (lane == 0) wsum[wid] = s;
    __syncthreads();
    if (tid == 0) bsum[blockIdx.x] = wsum[0] + wsum[1] + wsum[2] + wsum[3];
}

__global__ __launch_bounds__(64) void scanB_kernel(const unsigned* __restrict__ bsum,
                                                   unsigned* __restrict__ boff, int nb) {
    int lane = threadIdx.x;
    unsigned v = (lane < nb) ? bsum[lane] : 0u;
    unsigned incl = v;
    #pragma unroll
    for (int off = 1; off < 64; off <<= 1) {
        unsigned t = __shfl_up(incl, off, 64);
        if (lane >= off) incl += t;
    }
    if (lane < nb) boff[lane] = incl - v;
}

__global__ __launch_bounds__(256) void scanC_kernel(const unsigned* __restrict__ cnt,
                                                    const unsigned* __restrict__ boff,
                                                    unsigned* __restrict__ outp, int N) {
    __shared__ unsigned wsum[4];
    int tid = threadIdx.x, wid = tid >> 6, lane = tid & 63;
    int base = blockIdx.x * SCAN_CHUNK + tid * 8;
    unsigned v[8];
    unsigned s = 0;
    bool act = base < N;
    if (act) {
        uint4 a = *(const uint4*)(cnt + base);
        uint4 b = *(const uint4*)(cnt + base + 4);
        v[0] = a.x; v[1] = a.y; v[2] = a.z; v[3] = a.w;
        v[4] = b.x; v[5] = b.y; v[6] = b.z; v[7] = b.w;
        #pragma unroll
        for (int j = 0; j < 8; ++j) s += v[j];
    }
    unsigned incl = s;
    #pragma unroll
    for (int off = 1; off < 64; off <<= 1) {
        unsigned t = __shfl_up(incl, off, 64);
        if (lane >= off) incl += t;
    }
    if (lane == 63) wsum[wid] = incl;
    __syncthreads();
    unsigned woff = 0;
    for (int w = 0; w < 4; ++w) if (w < wid) woff += wsum[w];
    if (act) {
        unsigned run = incl - s + woff + boff[blockIdx.x];
        #pragma unroll
        for (int j = 0; j < 8; ++j) {
            outp[base + j] = run;
            run += v[j];
        }
    }
}

// ---------------- pass 3: scatter edges bin-contiguously (LDS cursors, no global atomics) ----------------
__global__ __launch_bounds__(256) void binscatter_kernel(const int* __restrict__ src,
                                                         const int* __restrict__ dst,
                                                         const unsigned* __restrict__ offs,
                                                         unsigned* __restrict__ bedge, int E) {
    __shared__ unsigned lcur[NBIN];
    int tid = threadIdx.x;
    if (tid < NBIN) lcur[tid] = offs[tid * NB2 + blockIdx.x];
    __syncthreads();
    int e0 = blockIdx.x * BCHUNK;
    int e1 = min(e0 + BCHUNK, E);
    for (int e = e0 + tid; e < e1; e += 256) {
        int d = dst[e];
        int b = d >> 10;
        unsigned pos = atomicAdd(&lcur[b], 1u);
        bedge[pos] = ((unsigned)src[e] << 10) | (unsigned)(d & 1023);
    }
}

// ---------------- pass 4: per-bin node counts -> rowptr, dinv, csr placement ----------------
__global__ __launch_bounds__(256) void bucket_kernel(const unsigned* __restrict__ bedge,
                                                     const unsigned* __restrict__ offs,
                                                     float* __restrict__ dinv,
                                                     unsigned* __restrict__ rowptr,
                                                     unsigned* __restrict__ csr_src, int N) {
    __shared__ unsigned lcnt[1024];
    __shared__ unsigned lcur[1024];
    __shared__ unsigned wsum[4];
    int b = blockIdx.x;
    int tid = threadIdx.x, wid = tid >> 6, lane = tid & 63;
    unsigned ebeg = offs[b * NB2], eend = offs[(b + 1) * NB2];
    lcnt[tid] = 0; lcnt[tid + 256] = 0; lcnt[tid + 512] = 0; lcnt[tid + 768] = 0;
    __syncthreads();
    for (unsigned e = ebeg + tid; e < eend; e += 256)
        atomicAdd(&lcnt[bedge[e] & 1023], 1u);
    __syncthreads();
    unsigned c[4];
    unsigned s = 0;
    #pragma unroll
    for (int j = 0; j < 4; ++j) { c[j] = lcnt[tid * 4 + j]; s += c[j]; }
    unsigned incl = s;
    #pragma unroll
    for (int off = 1; off < 64; off <<= 1) {
        unsigned t = __shfl_up(incl, off, 64);
        if (lane >= off) incl += t;
    }
    if (lane == 63) wsum[wid] = incl;
    __syncthreads();
    unsigned woff = 0;
    for (int w = 0; w < 4; ++w) if (w < wid) woff += wsum[w];
    unsigned run = (incl - s) + woff + ebeg;
    int gbase = b * 1024 + tid * 4;
    #pragma unroll
    for (int j = 0; j < 4; ++j) {
        if (gbase + j < N) {
            rowptr[gbase + j] = run;
            dinv[gbase + j] = rsqrtf((float)c[j] + 1.0f);
        }
        lcur[tid * 4 + j] = run;
        run += c[j];
    }
    if (b == NBIN - 1 && tid == 0) rowptr[N] = eend;
    __syncthreads();
    for (unsigned e = ebeg + tid; e < eend; e += 256) {
        unsigned v = bedge[e];
        unsigned pos = atomicAdd(&lcur[v & 1023], 1u);
        csr_src[pos] = v >> 10;
    }
}

// ---------------- norm precompute: csr_norm[e] = dinv[src[e]] * dinv[dst-node] ----------------
__global__ __launch_bounds__(256) void norm_kernel(const unsigned* __restrict__ csr_src,
                                                   const unsigned* __restrict__ rowptr,
                                                   const float* __restrict__ dinv,
                                                   float* __restrict__ csr_norm, int N) {
    int node = blockIdx.x * 256 + threadIdx.x;
    if (node >= N) return;
    float di = dinv[node];
    unsigned e = rowptr[node], end = rowptr[node + 1];
    for (; e < end; ++e) csr_norm[e] = dinv[csr_src[e]] * di;
}

// ---------------- W -> lane-ordered bf16 MFMA fragments ----------------
__global__ __launch_bounds__(256) void wprep_kernel(const float* __restrict__ Ws,
                                                    short* __restrict__ Wf) {
    int l = blockIdx.x;
    for (int idx = threadIdx.x; idx < 16384; idx += 256) {
        int i = idx & 7;
        int lane = (idx >> 3) & 63;
        int ns = idx >> 9;
        int s = ns & 3, nt = ns >> 2;
        int k = s * 32 + (lane >> 4) * 8 + i;
        int n = nt * 16 + (lane & 15);
        Wf[l * 16384 + idx] = (short)f2bf(Ws[l * 16384 + k * NF + n]);
    }
}

// ---------------- H = X @ W via bf16 MFMA; output bf16 ----------------
template<bool L0>
__global__ __launch_bounds__(256) void gemm_mfma_kernel(const void* __restrict__ Xin,
                                                        const short* __restrict__ Wf,
                                                        ushort* __restrict__ Hb, int M) {
    __shared__ short Wl[16384];
    int tid = threadIdx.x;
    for (int i = tid; i < 2048; i += 256)
        ((float4*)Wl)[i] = ((const float4*)Wf)[i];

    int wave = tid >> 6, lane = tid & 63;
    int r = lane & 15, kg = lane >> 4;
    int rowbase = blockIdx.x * 128 + wave * 32;

    bf16x8 afrag[2][4];
    #pragma unroll
    for (int t = 0; t < 2; ++t) {
        #pragma unroll
        for (int s = 0; s < 4; ++s) {
            int row = rowbase + t * 16 + r;
            if (row > M - 1) row = M - 1;
            if (L0) {
                const float* p = (const float*)Xin + (size_t)row * NF + s * 32 + kg * 8;
                float4 u0 = *(const float4*)p;
                float4 u1 = *(const float4*)(p + 4);
                bf16x8 a;
                a[0] = (short)f2bf(u0.x); a[1] = (short)f2bf(u0.y);
                a[2] = (short)f2bf(u0.z); a[3] = (short)f2bf(u0.w);
                a[4] = (short)f2bf(u1.x); a[5] = (short)f2bf(u1.y);
                a[6] = (short)f2bf(u1.z); a[7] = (short)f2bf(u1.w);
                afrag[t][s] = a;
            } else {
                afrag[t][s] = *(const bf16x8*)((const ushort*)Xin + (size_t)row * NF + s * 32 + kg * 8);
            }
        }
    }

    f32x4 acc[2][8];
    #pragma unroll
    for (int t = 0; t < 2; ++t)
        #pragma unroll
        for (int n = 0; n < 8; ++n)
            acc[t][n] = (f32x4){0.f, 0.f, 0.f, 0.f};

    __syncthreads();
    const bf16x8* WL = (const bf16x8*)Wl;
    #pragma unroll
    for (int s = 0; s < 4; ++s) {
        #pragma unroll
        for (int n = 0; n < 8; ++n) {
            bf16x8 bfr = WL[(n * 4 + s) * 64 + lane];
            acc[0][n] = __builtin_amdgcn_mfma_f32_16x16x32_bf16(afrag[0][s], bfr, acc[0][n], 0, 0, 0);
            acc[1][n] = __builtin_amdgcn_mfma_f32_16x16x32_bf16(afrag[1][s], bfr, acc[1][n], 0, 0, 0);
        }
    }

    int r4 = kg * 4;
    #pragma unroll
    for (int t = 0; t < 2; ++t) {
        #pragma unroll
        for (int n = 0; n < 8; ++n) {
            #pragma unroll
            for (int q = 0; q < 4; ++q) {
                int row = rowbase + t * 16 + r4 + q;
                if (row < M) Hb[(size_t)row * NF + n * 16 + r] = f2bf(acc[t][n][q]);
            }
        }
    }
}

// ---------------- aggregate: bf16 gather + precomputed norm; LAST fuses max-pool ----------------
// 12500 blocks x 256 thr; block = 8 consecutive nodes (exactly 100000 -> no tail).
template<bool LAST>
__global__ __launch_bounds__(256) void aggregate_kernel(const ushort* __restrict__ Hb,
                                                        const float* __restrict__ dinv,
                                                        const unsigned* __restrict__ rowptr,
                                                        const unsigned* __restrict__ csr_src,
                                                        const float* __restrict__ csr_norm,
                                                        const float* __restrict__ bias,
                                                        const int* __restrict__ batch,
                                                        ushort* __restrict__ Xout,
                                                        unsigned* __restrict__ Gx, int N) {
    __shared__ unsigned lmax[4][NF];   // only used when LAST
    __shared__ int g0s;
    int tid = threadIdx.x;
    int gid = blockIdx.x * 256 + tid;
    int node = gid >> 5;
    int lane = gid & 31;
    if (LAST) {
        if (tid == 0) g0s = batch[blockIdx.x * 8];
        for (int i = tid; i < 4 * NF; i += 256) ((unsigned*)lmax)[i] = 0;
        __syncthreads();
    }
    float di = dinv[node];
    float sl = di * di;
    float4 b = ((const float4*)bias)[lane];
    ushort4 hv = *(const ushort4*)(Hb + (size_t)node * NF + lane * 4);
    float ax = fmaf(b2f(hv.x), sl, b.x);
    float ay = fmaf(b2f(hv.y), sl, b.y);
    float az = fmaf(b2f(hv.z), sl, b.z);
    float aw = fmaf(b2f(hv.w), sl, b.w);
    unsigned e = rowptr[node], end = rowptr[node + 1];
    for (; e + 4 <= end; e += 4) {
        unsigned s0 = csr_src[e + 0], s1 = csr_src[e + 1];
        unsigned s2 = csr_src[e + 2], s3 = csr_src[e + 3];
        float n0 = csr_norm[e + 0], n1 = csr_norm[e + 1];
        float n2 = csr_norm[e + 2], n3 = csr_norm[e + 3];
        ushort4 g0 = *(const ushort4*)(Hb + (size_t)s0 * NF + lane * 4);
        ushort4 g1 = *(const ushort4*)(Hb + (size_t)s1 * NF + lane * 4);
        ushort4 g2 = *(const ushort4*)(Hb + (size_t)s2 * NF + lane * 4);
        ushort4 g3 = *(const ushort4*)(Hb + (size_t)s3 * NF + lane * 4);
        ax = fmaf(b2f(g0.x), n0, ax); ay = fmaf(b2f(g0.y), n0, ay);
        az = fmaf(b2f(g0.z), n0, az); aw = fmaf(b2f(g0.w), n0, aw);
        ax = fmaf(b2f(g1.x), n1, ax); ay = fmaf(b2f(g1.y), n1, ay);
        az = fmaf(b2f(g1.z), n1, az); aw = fmaf(b2f(g1.w), n1, aw);
        ax = fmaf(b2f(g2.x), n2, ax); ay = fmaf(b2f(g2.y), n2, ay);
        az = fmaf(b2f(g2.z), n2, az); aw = fmaf(b2f(g2.w), n2, aw);
        ax = fmaf(b2f(g3.x), n3, ax); ay = fmaf(b2f(g3.y), n3, ay);
        az = fmaf(b2f(g3.z), n3, az); aw = fmaf(b2f(g3.w), n3, aw);
    }
    for (; e < end; ++e) {
        unsigned s = csr_src[e];
        float nm = csr_norm[e];
        ushort4 g = *(const ushort4*)(Hb + (size_t)s * NF + lane * 4);
        ax = fmaf(b2f(g.x), nm, ax); ay = fmaf(b2f(g.y), nm, ay);
        az = fmaf(b2f(g.z), nm, az); aw = fmaf(b2f(g.w), nm, aw);
    }
    ax = ax > 0.f ? ax : expm1f(ax);
    ay = ay > 0.f ? ay : expm1f(ay);
    az = az > 0.f ? az : expm1f(az);
    aw = aw > 0.f ? aw : expm1f(aw);
    if (!LAST) {
        ushort4 o;
        o.x = f2bf(ax); o.y = f2bf(ay); o.z = f2bf(az); o.w = f2bf(aw);
        *(ushort4*)(Xout + (size_t)node * NF + lane * 4) = o;
    } else {
        // fused global max pool: LDS 4-slot combine, then per-block flush
        unsigned e0 = fenc(ax), e1 = fenc(ay), e2 = fenc(az), e3 = fenc(aw);
        int g = batch[node];
        int slot = g - g0s;
        int f0 = lane * 4;
        if (slot < 4) {
            atomicMax(&lmax[slot][f0 + 0], e0);
            atomicMax(&lmax[slot][f0 + 1], e1);
            atomicMax(&lmax[slot][f0 + 2], e2);
            atomicMax(&lmax[slot][f0 + 3], e3);
        } else {  // rare: block spans >4 graphs
            unsigned* p = Gx + (size_t)g * NF + f0;
            atomicMax(p + 0, e0); atomicMax(p + 1, e1);
            atomicMax(p + 2, e2); atomicMax(p + 3, e3);
        }
        __syncthreads();
        for (int i = tid; i < 4 * NF; i += 256) {
            unsigned v = ((unsigned*)lmax)[i];
            if (v) atomicMax(&Gx[(size_t)(g0s + (i >> 7)) * NF + (i & (NF - 1))], v);
        }
    }
}

// ---------------- classifier: softmax(decode(Gx) @ Wc + bc), fp32 ----------------
__global__ __launch_bounds__(128) void classify_kernel(const unsigned* __restrict__ Gx,
                                                       const float* __restrict__ Wc,
                                                       const float* __restrict__ bc,
                                                       float* __restrict__ out) {
    __shared__ float gr[NF];
    __shared__ float lg[NCLASSES];
    int g = blockIdx.x;
    int tid = threadIdx.x;
    gr[tid] = fdec(Gx[(size_t)g * NF + tid]);
    __syncthreads();
    if (tid < NCLASSES) {
        float s = bc[tid];
        for (int k = 0; k < NF; ++k) s = fmaf(gr[k], Wc[k * NCLASSES + tid], s);
        lg[tid] = s;
    }
    __syncthreads();
    if (tid == 0) {
        float m = lg[0];
        #pragma unroll
        for (int c = 1; c < NCLASSES; ++c) m = fmaxf(m, lg[c]);
        float e[NCLASSES];
        float sum = 0.f;
        #pragma unroll
        for (int c = 0; c < NCLASSES; ++c) { e[c] = expf(lg[c] - m); sum += e[c]; }
        #pragma unroll
        for (int c = 0; c < NCLASSES; ++c) out[g * NCLASSES + c] = e[c] / sum;
    }
}

extern "C" void kernel_launch(void* const* d_in, const int* in_sizes, int n_in,
                              void* d_out, int out_size, void* d_ws, size_t ws_size,
                              hipStream_t stream) {
    const float* x     = (const float*)d_in[0];
    const int*   ei    = (const int*)d_in[1];
    const int*   batch = (const int*)d_in[2];
    const float* Ws    = (const float*)d_in[3];
    const float* bs    = (const float*)d_in[4];
    const float* Wc    = (const float*)d_in[5];
    const float* bc    = (const float*)d_in[6];
    float* out = (float*)d_out;

    const int* src = ei;
    const int* dst = ei + NEDGES;

    char* ws = (char*)d_ws;
    size_t off = 0;
    auto alloc = [&](size_t bytes) -> void* {
        off = (off + 255) & ~(size_t)255;
        void* p = ws + off;
        off += bytes;
        return p;
    };
    ushort*   B0       = (ushort*)alloc(sizeof(ushort) * (size_t)NNODES * NF);
    ushort*   B1       = (ushort*)alloc(sizeof(ushort) * (size_t)NNODES * NF);
    ushort*   Hb       = (ushort*)alloc(sizeof(ushort) * (size_t)NNODES * NF);
    float*    dinvp    = (float*)alloc(sizeof(float) * NNODES);
    unsigned* rowptr   = (unsigned*)alloc(sizeof(unsigned) * (NNODES + 1));
    unsigned* csr_src  = (unsigned*)alloc(sizeof(unsigned) * NEDGES);
    float*    csr_norm = (float*)alloc(sizeof(float) * NEDGES);
    unsigned* bedge    = (unsigned*)alloc(sizeof(unsigned) * NEDGES);
    unsigned* offs     = (unsigned*)alloc(sizeof(unsigned) * (CNTS_PAD + 1));
    unsigned* bsum     = (unsigned*)alloc(sizeof(unsigned) * 16);
    unsigned* boff     = (unsigned*)alloc(sizeof(unsigned) * 16);
    short*    Wf       = (short*)alloc(sizeof(short) * 3 * 16384);
    // zero-region: cnts + Gx contiguous -> single memset
    unsigned* cnts     = (unsigned*)alloc(sizeof(unsigned) * CNTS_PAD);
    unsigned* Gx       = (unsigned*)alloc(sizeof(unsigned) * NGRAPHS * NF);
    size_t zspan = (size_t)((char*)(Gx + NGRAPHS * NF) - (char*)cnts);

    hipMemsetAsync(cnts, 0, zspan, stream);
    wprep_kernel<<<3, 256, 0, stream>>>(Ws, Wf);
    binct_kernel<<<NB2, 256, 0, stream>>>(dst, cnts, NEDGES);
    scanA_kernel<<<CNTS_PAD / SCAN_CHUNK, 256, 0, stream>>>(cnts, bsum, CNTS_PAD);
    scanB_kernel<<<1, 64, 0, stream>>>(bsum, boff, CNTS_PAD / SCAN_CHUNK);
    scanC_kernel<<<CNTS_PAD / SCAN_CHUNK, 256, 0, stream>>>(cnts, boff, offs, CNTS_PAD);
    binscatter_kernel<<<NB2, 256, 0, stream>>>(src, dst, offs, bedge, NEDGES);
    bucket_kernel<<<NBIN, 256, 0, stream>>>(bedge, offs, dinvp, rowptr, csr_src, NNODES);
    norm_kernel<<<(NNODES + 255) / 256, 256, 0, stream>>>(csr_src, rowptr, dinvp, csr_norm, NNODES);

    int gemm_grid = (NNODES + 127) / 128;   // 782
    int agg_grid  = (NNODES * 32) / 256;    // 12500 exact (8 nodes/block)

    gemm_mfma_kernel<true><<<gemm_grid, 256, 0, stream>>>(x, Wf + 0 * 16384, Hb, NNODES);
    aggregate_kernel<false><<<agg_grid, 256, 0, stream>>>(Hb, dinvp, rowptr, csr_src, csr_norm,
                                                          bs + 0 * NF, batch, B1, Gx, NNODES);
    gemm_mfma_kernel<false><<<gemm_grid, 256, 0, stream>>>(B1, Wf + 1 * 16384, Hb, NNODES);
    aggregate_kernel<false><<<agg_grid, 256, 0, stream>>>(Hb, dinvp, rowptr, csr_src, csr_norm,
                                                          bs + 1 * NF, batch, B0, Gx, NNODES);
    gemm_mfma_kernel<false><<<gemm_grid, 256, 0, stream>>>(B0, Wf + 2 * 16384, Hb, NNODES);
    aggregate_kernel<true><<<agg_grid, 256, 0, stream>>>(Hb, dinvp, rowptr, csr_src, csr_norm,
                                                         bs + 2 * NF, batch, (ushort*)nullptr, Gx, NNODES);

    classify_kernel<<<NGRAPHS, 128, 0, stream>>>(Gx, Wc, bc, out);
}